// Round 19
// baseline (590.667 us; speedup 1.0000x reference)
//
#include <hip/hip_runtime.h>
#include <hip/hip_bf16.h>
#include <hip/hip_fp16.h>

using bf16 = __hip_bfloat16;
typedef short short8 __attribute__((ext_vector_type(8)));
typedef float floatx4 __attribute__((ext_vector_type(4)));

#define LSEQ 401
#define NTOK 12832     // 32*401
#define NTOKP 12928    // padded to 101*128 (= 202*64)
#define DM 192
#define DI 384
#define NB 32
#define NCH 26         // time chunks
#define CHT 16         // chunk length
#define SLAB ((long)NTOKP * 44)
#define LOG2E 1.4426950408889634f

// ---- fp32 weights region layout (element offsets) ----
#define O_IMGS   0
#define O_PW     51200
#define O_PB     51968
#define O_CLS    52160
#define O_POS    52352
#define O_NORMW  129344
#define O_INW    130112
#define O_CONVW  719936
#define O_CONVB  726080
#define O_XPW    727616
#define O_DTW    795200
#define O_DTB    813632
#define O_ALOG   815168
#define O_DS     839744
#define O_OUTW   841280
#define O_NORMF  1136192
#define O_HEADW  1136384
#define O_HEADB  1328384
#define WTOT     1329408

// bf16 transposed-weight region (ushort element offsets within bfw)
#define BO_INWT  0         // 4 x [768][192]
#define BO_XPWT  589824    // 4 x [64][384] (rows 44..63 zero)
#define BO_OUTWT 688128    // 4 x [192][384]
#define BFTOT_F  491520    // ushorts 983040 => floats 491520

__constant__ int g_sz[18] = {51200, 768, 192, 192, 76992, 768, 589824, 6144, 1536,
                             67584, 18432, 1536, 24576, 1536, 294912, 192, 192000, 1000};
__constant__ int g_off[18] = {O_IMGS, O_PW, O_PB, O_CLS, O_POS, O_NORMW, O_INW, O_CONVW,
                              O_CONVB, O_XPW, O_DTW, O_DTB, O_ALOG, O_DS, O_OUTW,
                              O_NORMF, O_HEADW, O_HEADB};

struct SrcPtrs { const void* p[18]; };

static __device__ __forceinline__ int probe_flag(const unsigned short* probe) {
    unsigned short u0 = probe[0];
    if (u0 == 0x3F80u) return 0;  // bf16 (1.0)
    if (u0 == 0x3C00u) return 2;  // fp16 (1.0)
    return 1;                     // fp32
}
static __device__ __forceinline__ float load_src(int flag, const void* p, long i) {
    if (flag == 0) return __bfloat162float(((const bf16*)p)[i]);
    if (flag == 2) return __half2float(((const __half*)p)[i]);
    return ((const float*)p)[i];
}
static __device__ __forceinline__ unsigned short f2b(float f) {
    bf16 h = __float2bfloat16(f);
    return *reinterpret_cast<unsigned short*>(&h);
}
static __device__ __forceinline__ float b2f_us(unsigned short us) {
    unsigned int ui = (unsigned int)us << 16;
    return __uint_as_float(ui);
}
static __device__ __forceinline__ float exp2fast(float x) {
    return __builtin_amdgcn_exp2f(x);
}

// ---------------- unified ingest: fp32 copies (jobs 0-17) + bf16 transposed
// GEMM weights (jobs 18-20, layer = blockIdx.z) ----------------
__global__ void ingest_kernel(SrcPtrs sp, const unsigned short* __restrict__ probe,
                              float* __restrict__ dst, unsigned short* __restrict__ bfw) {
    int flag = probe_flag(probe);
    int which = blockIdx.y;
    if (which < 18) {
        int n = g_sz[which];
        const void* src = sp.p[which];
        float* d = dst + g_off[which];
        int stride = gridDim.x * gridDim.z * 256;
        int start = (blockIdx.z * gridDim.x + blockIdx.x) * 256 + threadIdx.x;
        for (int i = start; i < n; i += stride)
            d[i] = load_src(flag, src, i);
        return;
    }
    int layer = blockIdx.z;
    int stride = gridDim.x * 256;
    int start = blockIdx.x * 256 + threadIdx.x;
    if (which == 18) {                      // in_w [192][768] -> [768][192]
        for (int i = start; i < 768 * 192; i += stride) {
            int n = i / 192, k = i % 192;
            float v = load_src(flag, sp.p[6], (long)layer * 147456 + (long)k * 768 + n);
            bfw[BO_INWT + (long)layer * 147456 + i] = f2b(v);
        }
    } else if (which == 19) {               // xp_w [384][44] -> [64][384] zero-padded
        for (int i = start; i < 64 * 384; i += stride) {
            int n = i / 384, k = i % 384;
            float v = (n < 44) ? load_src(flag, sp.p[9], (long)layer * 16896 + (long)k * 44 + n) : 0.f;
            bfw[BO_XPWT + (long)layer * 24576 + i] = f2b(v);
        }
    } else {                                // out_w [384][192] -> [192][384]
        for (int i = start; i < 192 * 384; i += stride) {
            int n = i / 384, k = i % 384;
            float v = load_src(flag, sp.p[14], (long)layer * 73728 + (long)k * 192 + n);
            bfw[BO_OUTWT + (long)layer * 73728 + i] = f2b(v);
        }
    }
}

// ---------------- residual + rmsnorm -> res fp32, h bf16 (layer 0: fused embed) ------
// x input is bf16 (out_proj output) for layers 1-3
__global__ __launch_bounds__(256) void resnorm_kernel(
    const unsigned short* __restrict__ xb, float* __restrict__ res,
    unsigned short* __restrict__ hbf, const float* __restrict__ w,
    const float* __restrict__ W, int first) {
    int wv = threadIdx.x >> 6, lane = threadIdx.x & 63;
    long tok = (long)blockIdx.x * 4 + wv;
    long base = tok * DM + lane * 4;
    float4 v = make_float4(0.f, 0.f, 0.f, 0.f);
    bool real = (tok < NTOK);
    if (real && lane < 48) {
        if (first) {
            int b = (int)(tok / LSEQ), t = (int)(tok % LSEQ);
            int c = lane * 4;
            if (t < 400) {
                float s0 = W[O_IMGS + b * 1600 + t * 4 + 0];
                float s1 = W[O_IMGS + b * 1600 + t * 4 + 1];
                float s2 = W[O_IMGS + b * 1600 + t * 4 + 2];
                float s3 = W[O_IMGS + b * 1600 + t * 4 + 3];
                float4 p0 = *(const float4*)(W + O_PW + 0 * DM + c);
                float4 p1 = *(const float4*)(W + O_PW + 1 * DM + c);
                float4 p2 = *(const float4*)(W + O_PW + 2 * DM + c);
                float4 p3 = *(const float4*)(W + O_PW + 3 * DM + c);
                float4 pb = *(const float4*)(W + O_PB + c);
                float4 ps = *(const float4*)(W + O_POS + t * DM + c);
                v.x = s0 * p0.x + s1 * p1.x + s2 * p2.x + s3 * p3.x + pb.x + ps.x;
                v.y = s0 * p0.y + s1 * p1.y + s2 * p2.y + s3 * p3.y + pb.y + ps.y;
                v.z = s0 * p0.z + s1 * p1.z + s2 * p2.z + s3 * p3.z + pb.z + ps.z;
                v.w = s0 * p0.w + s1 * p1.w + s2 * p2.w + s3 * p3.w + pb.w + ps.w;
            } else {
                float4 cl = *(const float4*)(W + O_CLS + c);
                float4 ps = *(const float4*)(W + O_POS + 400 * DM + c);
                v.x = cl.x + ps.x; v.y = cl.y + ps.y;
                v.z = cl.z + ps.z; v.w = cl.w + ps.w;
            }
        } else {
            ushort4 xv = *(const ushort4*)(xb + base);
            float4 r = *(const float4*)(res + base);
            v.x = b2f_us(xv.x) + r.x; v.y = b2f_us(xv.y) + r.y;
            v.z = b2f_us(xv.z) + r.z; v.w = b2f_us(xv.w) + r.w;
        }
        *(float4*)(res + base) = v;
    }
    float ss = v.x * v.x + v.y * v.y + v.z * v.z + v.w * v.w;
#pragma unroll
    for (int o = 1; o < 64; o <<= 1) ss += __shfl_xor(ss, o, 64);
    float inv = rsqrtf(ss * (1.f / DM) + 1e-5f);
    if (lane < 48) {
        if (real) {
            float4 w4 = *(const float4*)(w + lane * 4);
            ushort4 h;
            h.x = f2b(v.x * inv * w4.x); h.y = f2b(v.y * inv * w4.y);
            h.z = f2b(v.z * inv * w4.z); h.w = f2b(v.w * inv * w4.w);
            *(ushort4*)(hbf + base) = h;
        } else if (tok < NTOKP) {
            ushort4 h; h.x = h.y = h.z = h.w = 0;
            *(ushort4*)(hbf + base) = h;
        }
    }
}

// ---------------- MFMA GEMM BM=64: C[tok][n] = sum_k A[tok][k] * Worig[k][n] ----------------
template <int OUTBF>
__global__ __launch_bounds__(256) void gemm_mfma(
    const unsigned short* __restrict__ A, const unsigned short* __restrict__ Wt,
    void* __restrict__ C, int K, int N, int NC) {
    __shared__ unsigned short sA[64][72];
    __shared__ unsigned short sW[64][72];
    int tid = threadIdx.x;
    int w = tid >> 6, lane = tid & 63;
    int q = lane >> 4, m = lane & 15;
    long tok0 = (long)blockIdx.x * 64;
    int n0 = blockIdx.y * 64;
    floatx4 acc[4] = {};
    for (int k0 = 0; k0 < K; k0 += 64) {
        int slot = tid;
#pragma unroll
        for (int i = 0; i < 2; ++i, slot += 256) {
            int r = slot >> 3, c8 = (slot & 7) * 8;
            *(short8*)&sA[r][c8] = *(const short8*)(A + (tok0 + r) * K + k0 + c8);
            *(short8*)&sW[r][c8] = *(const short8*)(Wt + (long)(n0 + r) * K + k0 + c8);
        }
        __syncthreads();
#pragma unroll
        for (int q2 = 0; q2 < 64; q2 += 32) {
            short8 bfr = *(const short8*)&sA[w * 16 + m][q2 + q * 8];
#pragma unroll
            for (int nt = 0; nt < 4; ++nt) {
                short8 afr = *(const short8*)&sW[nt * 16 + m][q2 + q * 8];
                acc[nt] = __builtin_amdgcn_mfma_f32_16x16x32_bf16(afr, bfr, acc[nt], 0, 0, 0);
            }
        }
        __syncthreads();
    }
    long tok = tok0 + w * 16 + m;
#pragma unroll
    for (int nt = 0; nt < 4; ++nt) {
        int ch = n0 + nt * 16 + q * 4;
        if (OUTBF) {
            unsigned short* dst = (unsigned short*)C + tok * NC + ch;
            ushort4 h4;
            h4.x = f2b(acc[nt][0]); h4.y = f2b(acc[nt][1]);
            h4.z = f2b(acc[nt][2]); h4.w = f2b(acc[nt][3]);
            *(ushort4*)dst = h4;
        } else {
            float* dst = (float*)C + tok * NC + ch;
            if (ch + 3 < N) {
                *(float4*)dst = make_float4(acc[nt][0], acc[nt][1], acc[nt][2], acc[nt][3]);
            } else {
#pragma unroll
                for (int r = 0; r < 4; ++r)
                    if (ch + r < N) dst[r] = acc[nt][r];
            }
        }
    }
}

// ---------------- MFMA GEMM BM=128 (in_proj only): bf16 out ----------------
__global__ __launch_bounds__(256) void gemm_mfma128(
    const unsigned short* __restrict__ A, const unsigned short* __restrict__ Wt,
    unsigned short* __restrict__ C, int K, int NC) {
    __shared__ unsigned short sA[128][72];
    __shared__ unsigned short sW[64][72];
    int tid = threadIdx.x;
    int w = tid >> 6, lane = tid & 63;
    int q = lane >> 4, m = lane & 15;
    long tok0 = (long)blockIdx.x * 128;
    int n0 = blockIdx.y * 64;
    floatx4 acc[2][4] = {};
    for (int k0 = 0; k0 < K; k0 += 64) {
#pragma unroll
        for (int p = 0; p < 4; ++p) {
            int idx = tid + p * 256;
            int r = idx >> 3, c8 = (idx & 7) * 8;
            *(short8*)&sA[r][c8] = *(const short8*)(A + (tok0 + r) * K + k0 + c8);
        }
#pragma unroll
        for (int p = 0; p < 2; ++p) {
            int idx = tid + p * 256;
            int r = idx >> 3, c8 = (idx & 7) * 8;
            *(short8*)&sW[r][c8] = *(const short8*)(Wt + (long)(n0 + r) * K + k0 + c8);
        }
        __syncthreads();
#pragma unroll
        for (int q2 = 0; q2 < 64; q2 += 32) {
#pragma unroll
            for (int tf = 0; tf < 2; ++tf) {
                short8 bfr = *(const short8*)&sA[w * 32 + tf * 16 + m][q2 + q * 8];
#pragma unroll
                for (int nt = 0; nt < 4; ++nt) {
                    short8 afr = *(const short8*)&sW[nt * 16 + m][q2 + q * 8];
                    acc[tf][nt] = __builtin_amdgcn_mfma_f32_16x16x32_bf16(afr, bfr, acc[tf][nt], 0, 0, 0);
                }
            }
        }
        __syncthreads();
    }
#pragma unroll
    for (int tf = 0; tf < 2; ++tf) {
        long tok = tok0 + w * 32 + tf * 16 + m;
#pragma unroll
        for (int nt = 0; nt < 4; ++nt) {
            int ch = n0 + nt * 16 + q * 4;
            ushort4 h4;
            h4.x = f2b(acc[tf][nt][0]); h4.y = f2b(acc[tf][nt][1]);
            h4.z = f2b(acc[tf][nt][2]); h4.w = f2b(acc[tf][nt][3]);
            *(ushort4*)((unsigned short*)C + tok * NC + ch) = h4;
        }
    }
}

// ---------------- fused conv+silu + x_proj GEMM (K-split): uc computed in staging ----------------
// also side-writes ucb (each k-split block covers a disjoint 128-wide k range)
__global__ __launch_bounds__(256) void gemm_xproj_conv(
    const unsigned short* __restrict__ xzb, const unsigned short* __restrict__ Wt,
    const float* __restrict__ cw, const float* __restrict__ cb,
    unsigned short* __restrict__ ucb, float* __restrict__ dblP) {
    __shared__ unsigned short sA[64][72];
    __shared__ unsigned short sW[64][72];
    __shared__ float scw[128][4];
    __shared__ float scb[128];
    int tid = threadIdx.x;
    int w = tid >> 6, lane = tid & 63;
    int q = lane >> 4, m = lane & 15;
    long tok0 = (long)blockIdx.x * 64;
    int koff = blockIdx.y * 128;
    float* C = dblP + (long)blockIdx.y * NTOKP * 44;
    if (tid < 128) {
        scb[tid] = cb[koff + tid];
        *(float4*)&scw[tid][0] = *(const float4*)(cw + (koff + tid) * 4);
    }
    floatx4 acc[4] = {};
    for (int k0 = 0; k0 < 128; k0 += 64) {
        if (k0 == 0) __syncthreads();   // scw/scb ready
        int slot = tid;
#pragma unroll
        for (int i = 0; i < 2; ++i, slot += 256) {
            int r = slot >> 3, c8 = (slot & 7) * 8;
            long tok = tok0 + r;
            int t = (int)(tok % LSEQ);
            int lk = k0 + c8;             // 0..127 within block's k range
            int kk = koff + lk;           // global channel
            float res[8];
#pragma unroll
            for (int jj = 0; jj < 8; ++jj) res[jj] = scb[lk + jj];
#pragma unroll
            for (int j = 0; j < 4; ++j) {  // tap j: weight col j multiplies u[t-3+j]
                int off = 3 - j;
                if (t >= off) {
                    short8 v = *(const short8*)(xzb + (tok - off) * 768 + kk);
#pragma unroll
                    for (int jj = 0; jj < 8; ++jj)
                        res[jj] = fmaf(scw[lk + jj][j], b2f_us((unsigned short)v[jj]), res[jj]);
                }
            }
            short8 h8;
#pragma unroll
            for (int jj = 0; jj < 8; ++jj) {
                float sv = res[jj] / (1.f + __expf(-res[jj]));
                h8[jj] = (short)f2b(sv);
            }
            *(short8*)&sA[r][c8] = h8;
            *(short8*)(ucb + tok * DI + kk) = h8;
            *(short8*)&sW[r][c8] = *(const short8*)(Wt + (long)r * DI + koff + k0 + c8);
        }
        __syncthreads();
#pragma unroll
        for (int q2 = 0; q2 < 64; q2 += 32) {
            short8 bfr = *(const short8*)&sA[w * 16 + m][q2 + q * 8];
#pragma unroll
            for (int nt = 0; nt < 4; ++nt) {
                short8 afr = *(const short8*)&sW[nt * 16 + m][q2 + q * 8];
                acc[nt] = __builtin_amdgcn_mfma_f32_16x16x32_bf16(afr, bfr, acc[nt], 0, 0, 0);
            }
        }
        __syncthreads();
    }
    long tok = tok0 + w * 16 + m;
#pragma unroll
    for (int nt = 0; nt < 4; ++nt) {
        int ch = nt * 16 + q * 4;
        float* dst = C + tok * 44 + ch;
        if (ch + 3 < 44) {
            *(float4*)dst = make_float4(acc[nt][0], acc[nt][1], acc[nt][2], acc[nt][3]);
        } else {
#pragma unroll
            for (int r = 0; r < 4; ++r)
                if (ch + r < 44) dst[r] = acc[nt][r];
        }
    }
}

// ---------------- S1: slab-sum staging; dt_proj+softplus; chunk summaries;
// z==0 blocks write compact dbl for S3 (delta recomputed there) ----------------
__global__ __launch_bounds__(256) void scan_sum_kernel(
    const float* __restrict__ dblP, const unsigned short* __restrict__ ucb,
    const float* __restrict__ dtw, const float* __restrict__ dtb,
    const float* __restrict__ Alog,
    float* __restrict__ Aprod, float* __restrict__ Hend, float* __restrict__ dbl) {
    int ch = blockIdx.x, b = blockIdx.y;
    int tid = threadIdx.x;
    int shalf = tid & 1;           // which 8 states
    int d = blockIdx.z * 128 + (tid >> 1);
    int t0 = ch * CHT;
    long tokb = (long)b * LSEQ + t0;
    int tmax = min(CHT, LSEQ - t0);
    bool last = (ch == NCH - 1);
    __shared__ float sdbl[CHT][44];
    for (int i = tid; i < tmax * 44; i += 256) {
        int r = i / 44, k = i % 44;
        long o = (tokb + r) * 44 + k;
        sdbl[r][k] = dblP[o] + dblP[o + SLAB] + dblP[o + 2 * SLAB];
    }
    float dtwr[12];
#pragma unroll
    for (int k = 0; k < 12; ++k) dtwr[k] = dtw[k * DI + d];
    float bias = dtb[d];
    float a[8];   // pre-scaled by log2(e): da = 2^(delta*a)
#pragma unroll
    for (int s = 0; s < 8; ++s) a[s] = -__expf(Alog[d * 16 + shalf * 8 + s]) * LOG2E;
    float h[8] = {};
    float sumd = 0.f;
    __syncthreads();
    // z==0 blocks persist the summed dbl rows for S3
    if (blockIdx.z == 0) {
        for (int i = tid; i < tmax * 44; i += 256) {
            int r = i / 44, k = i % 44;
            dbl[(tokb + r) * 44 + k] = sdbl[r][k];
        }
    }
    if (last) return;   // last chunk: no summary needed, S3 recomputes delta itself
    float u0 = b2f_us(ucb[tokb * DI + d]);
    float u1 = b2f_us(ucb[(tokb + min(1, tmax - 1)) * DI + d]);
#pragma unroll 2
    for (int t = 0; t < tmax; ++t) {
        int tp = min(t + 2, tmax - 1);
        float u2 = b2f_us(ucb[(tokb + tp) * DI + d]);
        float acc = bias;
#pragma unroll
        for (int k = 0; k < 12; ++k) acc = fmaf(sdbl[t][k], dtwr[k], acc);
        float delta = (acc > 20.f) ? acc : __logf(1.f + __expf(acc));
        float du = delta * u0;
        sumd += delta;
        float Bv[8];
        *(float4*)&Bv[0] = *(const float4*)&sdbl[t][12 + shalf * 8];
        *(float4*)&Bv[4] = *(const float4*)&sdbl[t][12 + shalf * 8 + 4];
#pragma unroll
        for (int s = 0; s < 8; ++s) {
            float da = exp2fast(delta * a[s]);
            h[s] = fmaf(da, h[s], du * Bv[s]);
        }
        u0 = u1; u1 = u2;
    }
    long idx = (((long)b * NCH + ch) * DI + d) * 16 + shalf * 8;
    float ap[8], he[8];
#pragma unroll
    for (int s = 0; s < 8; ++s) { ap[s] = exp2fast(a[s] * sumd); he[s] = h[s]; }
    *(float4*)(Aprod + idx) = *(float4*)&ap[0];
    *(float4*)(Aprod + idx + 4) = *(float4*)&ap[4];
    *(float4*)(Hend + idx) = *(float4*)&he[0];
    *(float4*)(Hend + idx + 4) = *(float4*)&he[4];
}

// ---------------- S2: combine chunk summaries -> h_init per chunk ----------------
__global__ __launch_bounds__(256) void scan_combine_kernel(
    const float* __restrict__ Ap, const float* __restrict__ He, float* __restrict__ hinit) {
    long gid = (long)blockIdx.x * 256 + threadIdx.x;   // < 32*6144
    int b = (int)(gid / 6144);
    int r = (int)(gid % 6144);
    float carry = 0.f;
#pragma unroll
    for (int j = 0; j < NCH; ++j) {
        long idx = ((long)b * NCH + j) * 6144 + r;
        hinit[idx] = carry;
        if (j < NCH - 1) carry = fmaf(Ap[idx], carry, He[idx]);
    }
}

// ---------------- S3: delta recompute + scan + D + gate -> ybf ----------------
__global__ __launch_bounds__(256) void scan_main_kernel(
    const unsigned short* __restrict__ ucb, const unsigned short* __restrict__ xzb,
    const float* __restrict__ dtw, const float* __restrict__ dtb,
    const float* __restrict__ Alog, const float* __restrict__ Dvec,
    const float* __restrict__ hinit, const float* __restrict__ dbl,
    unsigned short* __restrict__ ybf) {
    int ch = blockIdx.x, b = blockIdx.y;
    int tid = threadIdx.x;
    int shalf = tid & 1;
    int d = blockIdx.z * 128 + (tid >> 1);
    int t0 = ch * CHT;
    long tokb = (long)b * LSEQ + t0;
    int tmax = min(CHT, LSEQ - t0);
    __shared__ float sdt[CHT][12];
    __shared__ float sB[CHT][16], sC[CHT][16];
    for (int i = tid; i < CHT * 16; i += 256) {
        int r = i >> 4, s = i & 15;
        bool ok = (r < tmax);
        sB[r][s] = ok ? dbl[(tokb + r) * 44 + 12 + s] : 0.f;
        sC[r][s] = ok ? dbl[(tokb + r) * 44 + 28 + s] : 0.f;
    }
    for (int i = tid; i < tmax * 12; i += 256) {
        int r = i / 12, k = i % 12;
        sdt[r][k] = dbl[(tokb + r) * 44 + k];
    }
    float dtwr[12];
#pragma unroll
    for (int k = 0; k < 12; ++k) dtwr[k] = dtw[k * DI + d];
    float bias = dtb[d];
    float a[8];   // pre-scaled by log2(e)
#pragma unroll
    for (int s = 0; s < 8; ++s) a[s] = -__expf(Alog[d * 16 + shalf * 8 + s]) * LOG2E;
    float h[8];
    long hidx = (((long)b * NCH + ch) * DI + d) * 16 + shalf * 8;
    *(float4*)&h[0] = *(const float4*)(hinit + hidx);
    *(float4*)&h[4] = *(const float4*)(hinit + hidx + 4);
    float Dp = Dvec[d];
    __syncthreads();
    int t1i = min(1, tmax - 1);
    float u0 = b2f_us(ucb[tokb * DI + d]);
    float z0 = b2f_us(xzb[tokb * 768 + DI + d]);
    float u1 = b2f_us(ucb[(tokb + t1i) * DI + d]);
    float z1 = b2f_us(xzb[(tokb + t1i) * 768 + DI + d]);
#pragma unroll 2
    for (int t = 0; t < tmax; ++t) {
        int tp = min(t + 2, tmax - 1);
        float u2 = b2f_us(ucb[(tokb + tp) * DI + d]);
        float z2 = b2f_us(xzb[(tokb + tp) * 768 + DI + d]);
        // recompute delta (bit-identical to S1: same staged floats, same op order)
        float accd = bias;
#pragma unroll
        for (int k = 0; k < 12; ++k) accd = fmaf(sdt[t][k], dtwr[k], accd);
        float d0 = (accd > 20.f) ? accd : __logf(1.f + __expf(accd));
        float Bv[8], Cv[8];
        *(float4*)&Bv[0] = *(const float4*)&sB[t][shalf * 8];
        *(float4*)&Bv[4] = *(const float4*)&sB[t][shalf * 8 + 4];
        *(float4*)&Cv[0] = *(const float4*)&sC[t][shalf * 8];
        *(float4*)&Cv[4] = *(const float4*)&sC[t][shalf * 8 + 4];
        float du = d0 * u0;
        float y0 = 0.f, y1 = 0.f, y2 = 0.f, y3 = 0.f;
#pragma unroll
        for (int s = 0; s < 8; s += 4) {
            float da0 = exp2fast(d0 * a[s]);
            float da1 = exp2fast(d0 * a[s + 1]);
            float da2 = exp2fast(d0 * a[s + 2]);
            float da3 = exp2fast(d0 * a[s + 3]);
            h[s]     = fmaf(da0, h[s],     du * Bv[s]);
            h[s + 1] = fmaf(da1, h[s + 1], du * Bv[s + 1]);
            h[s + 2] = fmaf(da2, h[s + 2], du * Bv[s + 2]);
            h[s + 3] = fmaf(da3, h[s + 3], du * Bv[s + 3]);
            y0 = fmaf(h[s],     Cv[s],     y0);
            y1 = fmaf(h[s + 1], Cv[s + 1], y1);
            y2 = fmaf(h[s + 2], Cv[s + 2], y2);
            y3 = fmaf(h[s + 3], Cv[s + 3], y3);
        }
        float p = (y0 + y1) + (y2 + y3);
        p += __shfl_xor(p, 1, 64);
        if (shalf == 0) {
            float y = fmaf(u0, Dp, p);
            float gz = z0 / (1.f + __expf(-z0));
            ybf[(tokb + t) * DI + d] = f2b(y * gz);
        }
        u0 = u1; z0 = z1;
        u1 = u2; z1 = z2;
    }
}

// ---------------- head (fused final residual+rmsnorm at t=400; x is bf16) ----------------
__global__ __launch_bounds__(128) void head_kernel(
    const unsigned short* __restrict__ xb, const float* __restrict__ res,
    const float* __restrict__ nf, const float* __restrict__ hw,
    const float* __restrict__ hb, const unsigned short* __restrict__ probe,
    void* __restrict__ out) {
    int b = blockIdx.y;
    int n = blockIdx.x * 128 + threadIdx.x;
    long tok = (long)b * LSEQ + 400;
    __shared__ float vs[DM];
    __shared__ float red[2];
    float ss = 0.f;
    for (int i = threadIdx.x; i < DM; i += 128) {
        float v = b2f_us(xb[tok * DM + i]) + res[tok * DM + i];
        vs[i] = v;
        ss = fmaf(v, v, ss);
    }
#pragma unroll
    for (int o = 1; o < 64; o <<= 1) ss += __shfl_xor(ss, o, 64);
    if ((threadIdx.x & 63) == 0) red[threadIdx.x >> 6] = ss;
    __syncthreads();
    float inv = rsqrtf((red[0] + red[1]) * (1.f / DM) + 1e-5f);
    for (int i = threadIdx.x; i < DM; i += 128) vs[i] = vs[i] * inv * nf[i];
    __syncthreads();
    if (n < 1000) {
        float acc = hb[n];
#pragma unroll 4
        for (int c = 0; c < DM; ++c) acc = fmaf(vs[c], hw[c * 1000 + n], acc);
        int flag = probe_flag(probe);
        if (flag == 0)      ((bf16*)out)[b * 1000 + n] = (bf16)acc;
        else if (flag == 2) ((__half*)out)[b * 1000 + n] = __float2half(acc);
        else                ((float*)out)[b * 1000 + n] = acc;
    }
}

extern "C" void kernel_launch(void* const* d_in, const int* in_sizes, int n_in,
                              void* d_out, int out_size, void* d_ws, size_t ws_size,
                              hipStream_t stream) {
    float* ws = (float*)d_ws;
    float* Wr = ws;
    unsigned short* bfw = (unsigned short*)(ws + WTOT);
    float* act   = ws + WTOT + BFTOT_F;
    float* resT  = act;
    float* dbl   = resT + (long)NTOKP * DM;
    float* dblP  = dbl + (long)NTOKP * 44;
    float* Aprod = dblP + 3 * SLAB;
    float* Hend  = Aprod + (long)NB * NCH * 6144;
    float* hinit = Hend + (long)NB * NCH * 6144;
    unsigned short* xbB = (unsigned short*)(hinit + (long)NB * NCH * 6144);
    unsigned short* hbf = xbB + (long)NTOKP * DM;
    unsigned short* xzb = hbf + (long)NTOKP * DM;
    unsigned short* ucb = xzb + (long)NTOKP * 768;
    unsigned short* ybf = ucb + (long)NTOKP * DI;

    const unsigned short* probe = (const unsigned short*)d_in[5];  // norm_ws == ones

    SrcPtrs sp;
    for (int i = 0; i < 18; ++i) sp.p[i] = d_in[i];
    // unified ingest: fp32 copies + bf16 transposed weights, one dispatch
    ingest_kernel<<<dim3(144, 21, 4), 256, 0, stream>>>(sp, probe, Wr, bfw);

    for (int i = 0; i < 4; ++i) {
        // layer 0: fused embed + rmsnorm; layers 1-3: residual + rmsnorm (x in bf16)
        resnorm_kernel<<<NTOKP / 4, 256, 0, stream>>>(
            xbB, resT, hbf, Wr + O_NORMW + i * DM, Wr, i == 0);
        // in_proj: xzb[tok][768] bf16, K=192, BM=128
        gemm_mfma128<<<dim3(101, 12), 256, 0, stream>>>(
            hbf, bfw + BO_INWT + (long)i * 147456, xzb, 192, 768);
        // fused conv+silu + x_proj: K-split x3 partials (also writes ucb)
        gemm_xproj_conv<<<dim3(202, 3), 256, 0, stream>>>(
            xzb, bfw + BO_XPWT + (long)i * 24576,
            Wr + O_CONVW + i * 1536, Wr + O_CONVB + i * DI, ucb, dblP);
        // chunked scan: S1 (slab-sum staging, writes compact dbl + summaries),
        // S2 combine, S3 main (delta recomputed from compact dbl)
        scan_sum_kernel<<<dim3(NCH, NB, 3), 256, 0, stream>>>(
            dblP, ucb, Wr + O_DTW + i * 4608, Wr + O_DTB + i * DI,
            Wr + O_ALOG + i * 6144, Aprod, Hend, dbl);
        scan_combine_kernel<<<(NB * 6144) / 256, 256, 0, stream>>>(Aprod, Hend, hinit);
        scan_main_kernel<<<dim3(NCH, NB, 3), 256, 0, stream>>>(
            ucb, xzb, Wr + O_DTW + i * 4608, Wr + O_DTB + i * DI,
            Wr + O_ALOG + i * 6144, Wr + O_DS + i * DI, hinit, dbl, ybf);
        // out_proj: xbB[tok][192] bf16, K=384, BM=64
        gemm_mfma<1><<<dim3(202, 3), 256, 0, stream>>>(
            ybf, bfw + BO_OUTWT + (long)i * 73728, xbB, 384, 192, 192);
    }

    head_kernel<<<dim3(8, NB), 128, 0, stream>>>(
        xbB, resT, Wr + O_NORMF, Wr + O_HEADW, Wr + O_HEADB, probe, d_out);
}

// Round 20
// 578.107 us; speedup vs baseline: 1.0217x; 1.0217x over previous
//
#include <hip/hip_runtime.h>
#include <hip/hip_bf16.h>
#include <hip/hip_fp16.h>

using bf16 = __hip_bfloat16;
typedef short short8 __attribute__((ext_vector_type(8)));
typedef float floatx4 __attribute__((ext_vector_type(4)));

#define LSEQ 401
#define NTOK 12832     // 32*401
#define NTOKP 12928    // padded to 101*128 (= 202*64)
#define DM 192
#define DI 384
#define NB 32
#define NCH 26         // time chunks
#define CHT 16         // chunk length
#define SLAB ((long)NTOKP * 44)
#define LOG2E 1.4426950408889634f

// ---- fp32 weights region layout (element offsets) ----
#define O_IMGS   0
#define O_PW     51200
#define O_PB     51968
#define O_CLS    52160
#define O_POS    52352
#define O_NORMW  129344
#define O_INW    130112
#define O_CONVW  719936
#define O_CONVB  726080
#define O_XPW    727616
#define O_DTW    795200
#define O_DTB    813632
#define O_ALOG   815168
#define O_DS     839744
#define O_OUTW   841280
#define O_NORMF  1136192
#define O_HEADW  1136384
#define O_HEADB  1328384
#define WTOT     1329408

// bf16 transposed-weight region (ushort element offsets within bfw)
#define BO_INWT  0         // 4 x [768][192]
#define BO_XPWT  589824    // 4 x [64][384] (rows 44..63 zero)
#define BO_OUTWT 688128    // 4 x [192][384]
#define BFTOT_F  491520    // ushorts 983040 => floats 491520

__constant__ int g_sz[18] = {51200, 768, 192, 192, 76992, 768, 589824, 6144, 1536,
                             67584, 18432, 1536, 24576, 1536, 294912, 192, 192000, 1000};
__constant__ int g_off[18] = {O_IMGS, O_PW, O_PB, O_CLS, O_POS, O_NORMW, O_INW, O_CONVW,
                              O_CONVB, O_XPW, O_DTW, O_DTB, O_ALOG, O_DS, O_OUTW,
                              O_NORMF, O_HEADW, O_HEADB};

struct SrcPtrs { const void* p[18]; };

static __device__ __forceinline__ int probe_flag(const unsigned short* probe) {
    unsigned short u0 = probe[0];
    if (u0 == 0x3F80u) return 0;  // bf16 (1.0)
    if (u0 == 0x3C00u) return 2;  // fp16 (1.0)
    return 1;                     // fp32
}
static __device__ __forceinline__ float load_src(int flag, const void* p, long i) {
    if (flag == 0) return __bfloat162float(((const bf16*)p)[i]);
    if (flag == 2) return __half2float(((const __half*)p)[i]);
    return ((const float*)p)[i];
}
static __device__ __forceinline__ unsigned short f2b(float f) {
    bf16 h = __float2bfloat16(f);
    return *reinterpret_cast<unsigned short*>(&h);
}
static __device__ __forceinline__ float b2f_us(unsigned short us) {
    unsigned int ui = (unsigned int)us << 16;
    return __uint_as_float(ui);
}
static __device__ __forceinline__ float exp2fast(float x) {
    return __builtin_amdgcn_exp2f(x);
}

// ---------------- unified ingest: fp32 copies (jobs 0-17) + bf16 transposed
// GEMM weights (jobs 18-20, layer = blockIdx.z) ----------------
__global__ void ingest_kernel(SrcPtrs sp, const unsigned short* __restrict__ probe,
                              float* __restrict__ dst, unsigned short* __restrict__ bfw) {
    int flag = probe_flag(probe);
    int which = blockIdx.y;
    if (which < 18) {
        int n = g_sz[which];
        const void* src = sp.p[which];
        float* d = dst + g_off[which];
        int stride = gridDim.x * gridDim.z * 256;
        int start = (blockIdx.z * gridDim.x + blockIdx.x) * 256 + threadIdx.x;
        for (int i = start; i < n; i += stride)
            d[i] = load_src(flag, src, i);
        return;
    }
    int layer = blockIdx.z;
    int stride = gridDim.x * 256;
    int start = blockIdx.x * 256 + threadIdx.x;
    if (which == 18) {                      // in_w [192][768] -> [768][192]
        for (int i = start; i < 768 * 192; i += stride) {
            int n = i / 192, k = i % 192;
            float v = load_src(flag, sp.p[6], (long)layer * 147456 + (long)k * 768 + n);
            bfw[BO_INWT + (long)layer * 147456 + i] = f2b(v);
        }
    } else if (which == 19) {               // xp_w [384][44] -> [64][384] zero-padded
        for (int i = start; i < 64 * 384; i += stride) {
            int n = i / 384, k = i % 384;
            float v = (n < 44) ? load_src(flag, sp.p[9], (long)layer * 16896 + (long)k * 44 + n) : 0.f;
            bfw[BO_XPWT + (long)layer * 24576 + i] = f2b(v);
        }
    } else {                                // out_w [384][192] -> [192][384]
        for (int i = start; i < 192 * 384; i += stride) {
            int n = i / 384, k = i % 384;
            float v = load_src(flag, sp.p[14], (long)layer * 73728 + (long)k * 192 + n);
            bfw[BO_OUTWT + (long)layer * 73728 + i] = f2b(v);
        }
    }
}

// ---------------- residual + rmsnorm -> res fp32, h bf16 (layer 0: fused embed) ------
// x input is bf16 (out_proj output) for layers 1-3
__global__ __launch_bounds__(256) void resnorm_kernel(
    const unsigned short* __restrict__ xb, float* __restrict__ res,
    unsigned short* __restrict__ hbf, const float* __restrict__ w,
    const float* __restrict__ W, int first) {
    int wv = threadIdx.x >> 6, lane = threadIdx.x & 63;
    long tok = (long)blockIdx.x * 4 + wv;
    long base = tok * DM + lane * 4;
    float4 v = make_float4(0.f, 0.f, 0.f, 0.f);
    bool real = (tok < NTOK);
    if (real && lane < 48) {
        if (first) {
            int b = (int)(tok / LSEQ), t = (int)(tok % LSEQ);
            int c = lane * 4;
            if (t < 400) {
                float s0 = W[O_IMGS + b * 1600 + t * 4 + 0];
                float s1 = W[O_IMGS + b * 1600 + t * 4 + 1];
                float s2 = W[O_IMGS + b * 1600 + t * 4 + 2];
                float s3 = W[O_IMGS + b * 1600 + t * 4 + 3];
                float4 p0 = *(const float4*)(W + O_PW + 0 * DM + c);
                float4 p1 = *(const float4*)(W + O_PW + 1 * DM + c);
                float4 p2 = *(const float4*)(W + O_PW + 2 * DM + c);
                float4 p3 = *(const float4*)(W + O_PW + 3 * DM + c);
                float4 pb = *(const float4*)(W + O_PB + c);
                float4 ps = *(const float4*)(W + O_POS + t * DM + c);
                v.x = s0 * p0.x + s1 * p1.x + s2 * p2.x + s3 * p3.x + pb.x + ps.x;
                v.y = s0 * p0.y + s1 * p1.y + s2 * p2.y + s3 * p3.y + pb.y + ps.y;
                v.z = s0 * p0.z + s1 * p1.z + s2 * p2.z + s3 * p3.z + pb.z + ps.z;
                v.w = s0 * p0.w + s1 * p1.w + s2 * p2.w + s3 * p3.w + pb.w + ps.w;
            } else {
                float4 cl = *(const float4*)(W + O_CLS + c);
                float4 ps = *(const float4*)(W + O_POS + 400 * DM + c);
                v.x = cl.x + ps.x; v.y = cl.y + ps.y;
                v.z = cl.z + ps.z; v.w = cl.w + ps.w;
            }
        } else {
            ushort4 xv = *(const ushort4*)(xb + base);
            float4 r = *(const float4*)(res + base);
            v.x = b2f_us(xv.x) + r.x; v.y = b2f_us(xv.y) + r.y;
            v.z = b2f_us(xv.z) + r.z; v.w = b2f_us(xv.w) + r.w;
        }
        *(float4*)(res + base) = v;
    }
    float ss = v.x * v.x + v.y * v.y + v.z * v.z + v.w * v.w;
#pragma unroll
    for (int o = 1; o < 64; o <<= 1) ss += __shfl_xor(ss, o, 64);
    float inv = rsqrtf(ss * (1.f / DM) + 1e-5f);
    if (lane < 48) {
        if (real) {
            float4 w4 = *(const float4*)(w + lane * 4);
            ushort4 h;
            h.x = f2b(v.x * inv * w4.x); h.y = f2b(v.y * inv * w4.y);
            h.z = f2b(v.z * inv * w4.z); h.w = f2b(v.w * inv * w4.w);
            *(ushort4*)(hbf + base) = h;
        } else if (tok < NTOKP) {
            ushort4 h; h.x = h.y = h.z = h.w = 0;
            *(ushort4*)(hbf + base) = h;
        }
    }
}

// ---------------- MFMA GEMM BM=64: C[tok][n] = sum_k A[tok][k] * Worig[k][n] ----------------
template <int OUTBF>
__global__ __launch_bounds__(256) void gemm_mfma(
    const unsigned short* __restrict__ A, const unsigned short* __restrict__ Wt,
    void* __restrict__ C, int K, int N, int NC) {
    __shared__ unsigned short sA[64][72];
    __shared__ unsigned short sW[64][72];
    int tid = threadIdx.x;
    int w = tid >> 6, lane = tid & 63;
    int q = lane >> 4, m = lane & 15;
    long tok0 = (long)blockIdx.x * 64;
    int n0 = blockIdx.y * 64;
    floatx4 acc[4] = {};
    for (int k0 = 0; k0 < K; k0 += 64) {
        int slot = tid;
#pragma unroll
        for (int i = 0; i < 2; ++i, slot += 256) {
            int r = slot >> 3, c8 = (slot & 7) * 8;
            *(short8*)&sA[r][c8] = *(const short8*)(A + (tok0 + r) * K + k0 + c8);
            *(short8*)&sW[r][c8] = *(const short8*)(Wt + (long)(n0 + r) * K + k0 + c8);
        }
        __syncthreads();
#pragma unroll
        for (int q2 = 0; q2 < 64; q2 += 32) {
            short8 bfr = *(const short8*)&sA[w * 16 + m][q2 + q * 8];
#pragma unroll
            for (int nt = 0; nt < 4; ++nt) {
                short8 afr = *(const short8*)&sW[nt * 16 + m][q2 + q * 8];
                acc[nt] = __builtin_amdgcn_mfma_f32_16x16x32_bf16(afr, bfr, acc[nt], 0, 0, 0);
            }
        }
        __syncthreads();
    }
    long tok = tok0 + w * 16 + m;
#pragma unroll
    for (int nt = 0; nt < 4; ++nt) {
        int ch = n0 + nt * 16 + q * 4;
        if (OUTBF) {
            unsigned short* dst = (unsigned short*)C + tok * NC + ch;
            ushort4 h4;
            h4.x = f2b(acc[nt][0]); h4.y = f2b(acc[nt][1]);
            h4.z = f2b(acc[nt][2]); h4.w = f2b(acc[nt][3]);
            *(ushort4*)dst = h4;
        } else {
            float* dst = (float*)C + tok * NC + ch;
            if (ch + 3 < N) {
                *(float4*)dst = make_float4(acc[nt][0], acc[nt][1], acc[nt][2], acc[nt][3]);
            } else {
#pragma unroll
                for (int r = 0; r < 4; ++r)
                    if (ch + r < N) dst[r] = acc[nt][r];
            }
        }
    }
}

// ---------------- MFMA GEMM BM=128 (in_proj only): bf16 out ----------------
__global__ __launch_bounds__(256) void gemm_mfma128(
    const unsigned short* __restrict__ A, const unsigned short* __restrict__ Wt,
    unsigned short* __restrict__ C, int K, int NC) {
    __shared__ unsigned short sA[128][72];
    __shared__ unsigned short sW[64][72];
    int tid = threadIdx.x;
    int w = tid >> 6, lane = tid & 63;
    int q = lane >> 4, m = lane & 15;
    long tok0 = (long)blockIdx.x * 128;
    int n0 = blockIdx.y * 64;
    floatx4 acc[2][4] = {};
    for (int k0 = 0; k0 < K; k0 += 64) {
#pragma unroll
        for (int p = 0; p < 4; ++p) {
            int idx = tid + p * 256;
            int r = idx >> 3, c8 = (idx & 7) * 8;
            *(short8*)&sA[r][c8] = *(const short8*)(A + (tok0 + r) * K + k0 + c8);
        }
#pragma unroll
        for (int p = 0; p < 2; ++p) {
            int idx = tid + p * 256;
            int r = idx >> 3, c8 = (idx & 7) * 8;
            *(short8*)&sW[r][c8] = *(const short8*)(Wt + (long)(n0 + r) * K + k0 + c8);
        }
        __syncthreads();
#pragma unroll
        for (int q2 = 0; q2 < 64; q2 += 32) {
#pragma unroll
            for (int tf = 0; tf < 2; ++tf) {
                short8 bfr = *(const short8*)&sA[w * 32 + tf * 16 + m][q2 + q * 8];
#pragma unroll
                for (int nt = 0; nt < 4; ++nt) {
                    short8 afr = *(const short8*)&sW[nt * 16 + m][q2 + q * 8];
                    acc[tf][nt] = __builtin_amdgcn_mfma_f32_16x16x32_bf16(afr, bfr, acc[tf][nt], 0, 0, 0);
                }
            }
        }
        __syncthreads();
    }
#pragma unroll
    for (int tf = 0; tf < 2; ++tf) {
        long tok = tok0 + w * 32 + tf * 16 + m;
#pragma unroll
        for (int nt = 0; nt < 4; ++nt) {
            int ch = n0 + nt * 16 + q * 4;
            ushort4 h4;
            h4.x = f2b(acc[tf][nt][0]); h4.y = f2b(acc[tf][nt][1]);
            h4.z = f2b(acc[tf][nt][2]); h4.w = f2b(acc[tf][nt][3]);
            *(ushort4*)((unsigned short*)C + tok * NC + ch) = h4;
        }
    }
}

// ---------------- fused conv+silu + x_proj GEMM (K-split): uc computed in staging ----------------
// also side-writes ucb (each k-split block covers a disjoint 128-wide k range)
__global__ __launch_bounds__(256) void gemm_xproj_conv(
    const unsigned short* __restrict__ xzb, const unsigned short* __restrict__ Wt,
    const float* __restrict__ cw, const float* __restrict__ cb,
    unsigned short* __restrict__ ucb, float* __restrict__ dblP) {
    __shared__ unsigned short sA[64][72];
    __shared__ unsigned short sW[64][72];
    __shared__ float scw[128][4];
    __shared__ float scb[128];
    int tid = threadIdx.x;
    int w = tid >> 6, lane = tid & 63;
    int q = lane >> 4, m = lane & 15;
    long tok0 = (long)blockIdx.x * 64;
    int koff = blockIdx.y * 128;
    float* C = dblP + (long)blockIdx.y * NTOKP * 44;
    if (tid < 128) {
        scb[tid] = cb[koff + tid];
        *(float4*)&scw[tid][0] = *(const float4*)(cw + (koff + tid) * 4);
    }
    floatx4 acc[4] = {};
    for (int k0 = 0; k0 < 128; k0 += 64) {
        if (k0 == 0) __syncthreads();   // scw/scb ready
        int slot = tid;
#pragma unroll
        for (int i = 0; i < 2; ++i, slot += 256) {
            int r = slot >> 3, c8 = (slot & 7) * 8;
            long tok = tok0 + r;
            int t = (int)(tok % LSEQ);
            int lk = k0 + c8;             // 0..127 within block's k range
            int kk = koff + lk;           // global channel
            float res[8];
#pragma unroll
            for (int jj = 0; jj < 8; ++jj) res[jj] = scb[lk + jj];
#pragma unroll
            for (int j = 0; j < 4; ++j) {  // tap j: weight col j multiplies u[t-3+j]
                int off = 3 - j;
                if (t >= off) {
                    short8 v = *(const short8*)(xzb + (tok - off) * 768 + kk);
#pragma unroll
                    for (int jj = 0; jj < 8; ++jj)
                        res[jj] = fmaf(scw[lk + jj][j], b2f_us((unsigned short)v[jj]), res[jj]);
                }
            }
            short8 h8;
#pragma unroll
            for (int jj = 0; jj < 8; ++jj) {
                float sv = res[jj] / (1.f + __expf(-res[jj]));
                h8[jj] = (short)f2b(sv);
            }
            *(short8*)&sA[r][c8] = h8;
            *(short8*)(ucb + tok * DI + kk) = h8;
            *(short8*)&sW[r][c8] = *(const short8*)(Wt + (long)r * DI + koff + k0 + c8);
        }
        __syncthreads();
#pragma unroll
        for (int q2 = 0; q2 < 64; q2 += 32) {
            short8 bfr = *(const short8*)&sA[w * 16 + m][q2 + q * 8];
#pragma unroll
            for (int nt = 0; nt < 4; ++nt) {
                short8 afr = *(const short8*)&sW[nt * 16 + m][q2 + q * 8];
                acc[nt] = __builtin_amdgcn_mfma_f32_16x16x32_bf16(afr, bfr, acc[nt], 0, 0, 0);
            }
        }
        __syncthreads();
    }
    long tok = tok0 + w * 16 + m;
#pragma unroll
    for (int nt = 0; nt < 4; ++nt) {
        int ch = nt * 16 + q * 4;
        float* dst = C + tok * 44 + ch;
        if (ch + 3 < 44) {
            *(float4*)dst = make_float4(acc[nt][0], acc[nt][1], acc[nt][2], acc[nt][3]);
        } else {
#pragma unroll
            for (int r = 0; r < 4; ++r)
                if (ch + r < 44) dst[r] = acc[nt][r];
        }
    }
}

// ---------------- S1: slab-sum staging; dt_proj+softplus -> deltaBuf (bf16);
// chunk summaries; z==0 blocks write compact dbl for S3 ----------------
__global__ __launch_bounds__(256) void scan_sum_kernel(
    const float* __restrict__ dblP, const unsigned short* __restrict__ ucb,
    const float* __restrict__ dtw, const float* __restrict__ dtb,
    const float* __restrict__ Alog, unsigned short* __restrict__ deltaBuf,
    float* __restrict__ Aprod, float* __restrict__ Hend, float* __restrict__ dbl) {
    int ch = blockIdx.x, b = blockIdx.y;
    int tid = threadIdx.x;
    int shalf = tid & 1;           // which 8 states
    int d = blockIdx.z * 128 + (tid >> 1);
    int t0 = ch * CHT;
    long tokb = (long)b * LSEQ + t0;
    int tmax = min(CHT, LSEQ - t0);
    bool last = (ch == NCH - 1);
    __shared__ float sdbl[CHT][44];
    for (int i = tid; i < tmax * 44; i += 256) {
        int r = i / 44, k = i % 44;
        long o = (tokb + r) * 44 + k;
        sdbl[r][k] = dblP[o] + dblP[o + SLAB] + dblP[o + 2 * SLAB];
    }
    float dtwr[12];
#pragma unroll
    for (int k = 0; k < 12; ++k) dtwr[k] = dtw[k * DI + d];
    float bias = dtb[d];
    float a[8];   // pre-scaled by log2(e): da = 2^(delta*a)
#pragma unroll
    for (int s = 0; s < 8; ++s) a[s] = -__expf(Alog[d * 16 + shalf * 8 + s]) * LOG2E;
    float h[8] = {};
    float sumd = 0.f;
    __syncthreads();
    // z==0 blocks persist the summed dbl rows for S3
    if (blockIdx.z == 0) {
        for (int i = tid; i < tmax * 44; i += 256) {
            int r = i / 44, k = i % 44;
            dbl[(tokb + r) * 44 + k] = sdbl[r][k];
        }
    }
    float u0 = b2f_us(ucb[tokb * DI + d]);
    float u1 = b2f_us(ucb[(tokb + min(1, tmax - 1)) * DI + d]);
#pragma unroll 2
    for (int t = 0; t < tmax; ++t) {
        int tp = min(t + 2, tmax - 1);
        float u2 = b2f_us(ucb[(tokb + tp) * DI + d]);
        float acc = bias;
#pragma unroll
        for (int k = 0; k < 12; ++k) acc = fmaf(sdbl[t][k], dtwr[k], acc);
        float delta = (acc > 20.f) ? acc : __logf(1.f + __expf(acc));
        delta = b2f_us(f2b(delta));          // round once so S1 and S3 use identical delta
        if (shalf == 0) deltaBuf[(tokb + t) * DI + d] = f2b(delta);
        if (!last) {
            float du = delta * u0;
            sumd += delta;
            float Bv[8];
            *(float4*)&Bv[0] = *(const float4*)&sdbl[t][12 + shalf * 8];
            *(float4*)&Bv[4] = *(const float4*)&sdbl[t][12 + shalf * 8 + 4];
#pragma unroll
            for (int s = 0; s < 8; ++s) {
                float da = exp2fast(delta * a[s]);
                h[s] = fmaf(da, h[s], du * Bv[s]);
            }
        }
        u0 = u1; u1 = u2;
    }
    if (!last) {
        long idx = (((long)b * NCH + ch) * DI + d) * 16 + shalf * 8;
        float ap[8], he[8];
#pragma unroll
        for (int s = 0; s < 8; ++s) { ap[s] = exp2fast(a[s] * sumd); he[s] = h[s]; }
        *(float4*)(Aprod + idx) = *(float4*)&ap[0];
        *(float4*)(Aprod + idx + 4) = *(float4*)&ap[4];
        *(float4*)(Hend + idx) = *(float4*)&he[0];
        *(float4*)(Hend + idx + 4) = *(float4*)&he[4];
    }
}

// ---------------- S2: combine chunk summaries -> h_init per chunk ----------------
__global__ __launch_bounds__(256) void scan_combine_kernel(
    const float* __restrict__ Ap, const float* __restrict__ He, float* __restrict__ hinit) {
    long gid = (long)blockIdx.x * 256 + threadIdx.x;   // < 32*6144
    int b = (int)(gid / 6144);
    int r = (int)(gid % 6144);
    float carry = 0.f;
#pragma unroll
    for (int j = 0; j < NCH; ++j) {
        long idx = ((long)b * NCH + j) * 6144 + r;
        hinit[idx] = carry;
        if (j < NCH - 1) carry = fmaf(Ap[idx], carry, He[idx]);
    }
}

// ---------------- S3: scan + D + gate -> ybf (2 lanes per d, 8 states each) ----------------
__global__ __launch_bounds__(256) void scan_main_kernel(
    const unsigned short* __restrict__ deltaBuf, const unsigned short* __restrict__ ucb,
    const unsigned short* __restrict__ xzb, const float* __restrict__ Alog,
    const float* __restrict__ Dvec, const float* __restrict__ hinit,
    const float* __restrict__ dbl, unsigned short* __restrict__ ybf) {
    int ch = blockIdx.x, b = blockIdx.y;
    int tid = threadIdx.x;
    int shalf = tid & 1;
    int d = blockIdx.z * 128 + (tid >> 1);
    int t0 = ch * CHT;
    long tokb = (long)b * LSEQ + t0;
    int tmax = min(CHT, LSEQ - t0);
    __shared__ float sB[CHT][16], sC[CHT][16];
    for (int i = tid; i < CHT * 16; i += 256) {
        int r = i >> 4, s = i & 15;
        bool ok = (r < tmax);
        sB[r][s] = ok ? dbl[(tokb + r) * 44 + 12 + s] : 0.f;
        sC[r][s] = ok ? dbl[(tokb + r) * 44 + 28 + s] : 0.f;
    }
    float a[8];   // pre-scaled by log2(e)
#pragma unroll
    for (int s = 0; s < 8; ++s) a[s] = -__expf(Alog[d * 16 + shalf * 8 + s]) * LOG2E;
    float h[8];
    long hidx = (((long)b * NCH + ch) * DI + d) * 16 + shalf * 8;
    *(float4*)&h[0] = *(const float4*)(hinit + hidx);
    *(float4*)&h[4] = *(const float4*)(hinit + hidx + 4);
    float Dp = Dvec[d];
    __syncthreads();
    int t1i = min(1, tmax - 1);
    float d0 = b2f_us(deltaBuf[tokb * DI + d]);
    float u0 = b2f_us(ucb[tokb * DI + d]);
    float z0 = b2f_us(xzb[tokb * 768 + DI + d]);
    float d1 = b2f_us(deltaBuf[(tokb + t1i) * DI + d]);
    float u1 = b2f_us(ucb[(tokb + t1i) * DI + d]);
    float z1 = b2f_us(xzb[(tokb + t1i) * 768 + DI + d]);
#pragma unroll 2
    for (int t = 0; t < tmax; ++t) {
        int tp = min(t + 2, tmax - 1);
        float d2 = b2f_us(deltaBuf[(tokb + tp) * DI + d]);
        float u2 = b2f_us(ucb[(tokb + tp) * DI + d]);
        float z2 = b2f_us(xzb[(tokb + tp) * 768 + DI + d]);
        float Bv[8], Cv[8];
        *(float4*)&Bv[0] = *(const float4*)&sB[t][shalf * 8];
        *(float4*)&Bv[4] = *(const float4*)&sB[t][shalf * 8 + 4];
        *(float4*)&Cv[0] = *(const float4*)&sC[t][shalf * 8];
        *(float4*)&Cv[4] = *(const float4*)&sC[t][shalf * 8 + 4];
        float du = d0 * u0;
        float y0 = 0.f, y1 = 0.f, y2 = 0.f, y3 = 0.f;
#pragma unroll
        for (int s = 0; s < 8; s += 4) {
            float da0 = exp2fast(d0 * a[s]);
            float da1 = exp2fast(d0 * a[s + 1]);
            float da2 = exp2fast(d0 * a[s + 2]);
            float da3 = exp2fast(d0 * a[s + 3]);
            h[s]     = fmaf(da0, h[s],     du * Bv[s]);
            h[s + 1] = fmaf(da1, h[s + 1], du * Bv[s + 1]);
            h[s + 2] = fmaf(da2, h[s + 2], du * Bv[s + 2]);
            h[s + 3] = fmaf(da3, h[s + 3], du * Bv[s + 3]);
            y0 = fmaf(h[s],     Cv[s],     y0);
            y1 = fmaf(h[s + 1], Cv[s + 1], y1);
            y2 = fmaf(h[s + 2], Cv[s + 2], y2);
            y3 = fmaf(h[s + 3], Cv[s + 3], y3);
        }
        float p = (y0 + y1) + (y2 + y3);
        p += __shfl_xor(p, 1, 64);
        if (shalf == 0) {
            float y = fmaf(u0, Dp, p);
            float gz = z0 / (1.f + __expf(-z0));
            ybf[(tokb + t) * DI + d] = f2b(y * gz);
        }
        d0 = d1; u0 = u1; z0 = z1;
        d1 = d2; u1 = u2; z1 = z2;
    }
}

// ---------------- head (fused final residual+rmsnorm at t=400; x is bf16) ----------------
__global__ __launch_bounds__(128) void head_kernel(
    const unsigned short* __restrict__ xb, const float* __restrict__ res,
    const float* __restrict__ nf, const float* __restrict__ hw,
    const float* __restrict__ hb, const unsigned short* __restrict__ probe,
    void* __restrict__ out) {
    int b = blockIdx.y;
    int n = blockIdx.x * 128 + threadIdx.x;
    long tok = (long)b * LSEQ + 400;
    __shared__ float vs[DM];
    __shared__ float red[2];
    float ss = 0.f;
    for (int i = threadIdx.x; i < DM; i += 128) {
        float v = b2f_us(xb[tok * DM + i]) + res[tok * DM + i];
        vs[i] = v;
        ss = fmaf(v, v, ss);
    }
#pragma unroll
    for (int o = 1; o < 64; o <<= 1) ss += __shfl_xor(ss, o, 64);
    if ((threadIdx.x & 63) == 0) red[threadIdx.x >> 6] = ss;
    __syncthreads();
    float inv = rsqrtf((red[0] + red[1]) * (1.f / DM) + 1e-5f);
    for (int i = threadIdx.x; i < DM; i += 128) vs[i] = vs[i] * inv * nf[i];
    __syncthreads();
    if (n < 1000) {
        float acc = hb[n];
#pragma unroll 4
        for (int c = 0; c < DM; ++c) acc = fmaf(vs[c], hw[c * 1000 + n], acc);
        int flag = probe_flag(probe);
        if (flag == 0)      ((bf16*)out)[b * 1000 + n] = (bf16)acc;
        else if (flag == 2) ((__half*)out)[b * 1000 + n] = __float2half(acc);
        else                ((float*)out)[b * 1000 + n] = acc;
    }
}

extern "C" void kernel_launch(void* const* d_in, const int* in_sizes, int n_in,
                              void* d_out, int out_size, void* d_ws, size_t ws_size,
                              hipStream_t stream) {
    float* ws = (float*)d_ws;
    float* Wr = ws;
    unsigned short* bfw = (unsigned short*)(ws + WTOT);
    float* act   = ws + WTOT + BFTOT_F;
    float* resT  = act;
    float* dbl   = resT + (long)NTOKP * DM;
    float* dblP  = dbl + (long)NTOKP * 44;
    float* Aprod = dblP + 3 * SLAB;
    float* Hend  = Aprod + (long)NB * NCH * 6144;
    float* hinit = Hend + (long)NB * NCH * 6144;
    unsigned short* deltaB = (unsigned short*)(hinit + (long)NB * NCH * 6144);
    unsigned short* xbB = deltaB + (long)NTOKP * DI;     // bf16 layer output
    unsigned short* hbf = xbB + (long)NTOKP * DM;
    unsigned short* xzb = hbf + (long)NTOKP * DM;
    unsigned short* ucb = xzb + (long)NTOKP * 768;
    unsigned short* ybf = ucb + (long)NTOKP * DI;

    const unsigned short* probe = (const unsigned short*)d_in[5];  // norm_ws == ones

    SrcPtrs sp;
    for (int i = 0; i < 18; ++i) sp.p[i] = d_in[i];
    // unified ingest: fp32 copies + bf16 transposed weights, one dispatch
    ingest_kernel<<<dim3(144, 21, 4), 256, 0, stream>>>(sp, probe, Wr, bfw);

    for (int i = 0; i < 4; ++i) {
        // layer 0: fused embed + rmsnorm; layers 1-3: residual + rmsnorm (x in bf16)
        resnorm_kernel<<<NTOKP / 4, 256, 0, stream>>>(
            xbB, resT, hbf, Wr + O_NORMW + i * DM, Wr, i == 0);
        // in_proj: xzb[tok][768] bf16, K=192, BM=128
        gemm_mfma128<<<dim3(101, 12), 256, 0, stream>>>(
            hbf, bfw + BO_INWT + (long)i * 147456, xzb, 192, 768);
        // fused conv+silu + x_proj: K-split x3 partials (also writes ucb)
        gemm_xproj_conv<<<dim3(202, 3), 256, 0, stream>>>(
            xzb, bfw + BO_XPWT + (long)i * 24576,
            Wr + O_CONVW + i * 1536, Wr + O_CONVB + i * DI, ucb, dblP);
        // chunked scan: S1 (slab-sum staging, writes compact dbl + delta + summaries),
        // S2 combine, S3 main
        scan_sum_kernel<<<dim3(NCH, NB, 3), 256, 0, stream>>>(
            dblP, ucb, Wr + O_DTW + i * 4608, Wr + O_DTB + i * DI,
            Wr + O_ALOG + i * 6144, deltaB, Aprod, Hend, dbl);
        scan_combine_kernel<<<(NB * 6144) / 256, 256, 0, stream>>>(Aprod, Hend, hinit);
        scan_main_kernel<<<dim3(NCH, NB, 3), 256, 0, stream>>>(
            deltaB, ucb, xzb, Wr + O_ALOG + i * 6144, Wr + O_DS + i * DI,
            hinit, dbl, ybf);
        // out_proj: xbB[tok][192] bf16, K=384, BM=64
        gemm_mfma<1><<<dim3(202, 3), 256, 0, stream>>>(
            ybf, bfw + BO_OUTWT + (long)i * 73728, xbB, 384, 192, 192);
    }

    head_kernel<<<dim3(8, NB), 128, 0, stream>>>(
        xbB, resT, Wr + O_NORMF, Wr + O_HEADW, Wr + O_HEADB, probe, d_out);
}